// Round 2
// baseline (421.486 us; speedup 1.0000x reference)
//
#include <hip/hip_runtime.h>
#include <hip/hip_bf16.h>
#include <float.h>
#include <stdint.h>

#define NPT    4096
#define EMB    512
#define NH     8
#define HD     64
#define KSPLIT 32     // score k-range split: KRANGE = 128 (4 tiles of 32)

typedef __attribute__((ext_vector_type(8))) _Float16 f16x8;
typedef __attribute__((ext_vector_type(4))) float f32x4;
typedef uint32_t u32;

// low plane is stored scaled by 2^11 (exact) so it stays in fp16 normal range;
// recombine with s = hi_acc + lo_acc * 2^-11.
#define LO_SCALE 2048.0f
#define LO_INV   4.8828125e-4f   // 2^-11

// async global->LDS DMA, 16B/lane. LDS dest = wave-uniform base + lane*16.
__device__ __forceinline__ void async_ld16(const void* gsrc, void* ldst) {
    __builtin_amdgcn_global_load_lds(
        (const __attribute__((address_space(1))) u32*)gsrc,
        (__attribute__((address_space(3))) u32*)ldst, 16, 0, 0);
}

// fp16x2 split: a ~= h + l/2048, |err| <= 2^-22 |a|. 3-product GEMM drops
// l*l (~2^-22 per term, random sign) -> end-to-end error is fp32-accum-noise
// dominated, same regime as the fp32 reference.
__device__ __forceinline__ void split2(float a, unsigned short& h, unsigned short& l) {
    _Float16 fh = (_Float16)a;
    float r = (a - (float)fh) * LO_SCALE;
    _Float16 fl = (_Float16)r;
    h = *reinterpret_cast<unsigned short*>(&fh);
    l = *reinterpret_cast<unsigned short*>(&fl);
}

// ---------------------------------------------------------------------------
// 1) fused prep: y=0 split x; y=1..3 split W (granule-major); y=4 pack adj
//    into TRANSPOSED bitmask bits_t[kword(128)][q(4096)]
// ---------------------------------------------------------------------------
__global__ __launch_bounds__(256) void prep_kernel(const float* __restrict__ x,
                                                   const float* __restrict__ wq,
                                                   const float* __restrict__ wk,
                                                   const float* __restrict__ wv,
                                                   const int* __restrict__ adj,
                                                   unsigned short* __restrict__ xs,
                                                   unsigned short* __restrict__ wqs,
                                                   unsigned short* __restrict__ wks,
                                                   unsigned short* __restrict__ wvs,
                                                   unsigned* __restrict__ bits_t) {
    int y = blockIdx.y;
    size_t i = (size_t)blockIdx.x * 256 + threadIdx.x;
    if (y == 4) {                               // pack adj (reads coalesced)
        int q = (int)(i >> 7), w = (int)i & 127;
        const int4* p = (const int4*)(adj + (size_t)q * NPT + w * 32);
        unsigned m = 0;
#pragma unroll
        for (int j = 0; j < 8; ++j) {
            int4 v = p[j];
            m |= (v.x != 0 ? 1u : 0u) << (j * 4 + 0);
            m |= (v.y != 0 ? 1u : 0u) << (j * 4 + 1);
            m |= (v.z != 0 ? 1u : 0u) << (j * 4 + 2);
            m |= (v.w != 0 ? 1u : 0u) << (j * 4 + 3);
        }
        bits_t[(size_t)w * NPT + q] = m;        // transposed write (2 MB, cheap)
    } else if (y == 0) {
        const size_t PL = (size_t)NPT * EMB;
        float4 v = ((const float4*)x)[i];
        ushort4 h, l;
        split2(v.x, h.x, l.x);
        split2(v.y, h.y, l.y);
        split2(v.z, h.z, l.z);
        split2(v.w, h.w, l.w);
        ((ushort4*)xs)[i]        = h;
        ((ushort4*)(xs + PL))[i] = l;
    } else {
        const size_t WPL = 262144;
        if (i >= WPL / 4) return;
        const float* src = (y == 1) ? wq : (y == 2) ? wk : wv;
        unsigned short* dst = (y == 1) ? wqs : (y == 2) ? wks : wvs;
        float4 v = ((const float4*)src)[i];
        int e  = (int)(i >> 7);
        int k0 = ((int)i & 127) * 4;
        int ebk = e >> 6, el = e & 63;
        int kc = k0 >> 5, g = (k0 >> 3) & 3, dd = k0 & 7;
        size_t off = ((((size_t)ebk * 16 + kc) * 4 + g) * 64 + el) * 8 + dd;
        ushort4 h, l;
        split2(v.x, h.x, l.x);
        split2(v.y, h.y, l.y);
        split2(v.z, h.z, l.z);
        split2(v.w, h.w, l.w);
        *(ushort4*)(dst + off)       = h;
        *(ushort4*)(dst + WPL + off) = l;
    }
}

// ---------------------------------------------------------------------------
// 2) projections via fp16x2 3-product MFMA. Counted-vmcnt barrier (no drain).
//    Q2/K2 granule-major: [h][t32(128)][dg(8)][i32(32)][8shorts], 2 planes.
// ---------------------------------------------------------------------------
__global__ __launch_bounds__(256, 3) void gemm_mfma(const unsigned short* __restrict__ xs,
                                                    const unsigned short* __restrict__ wqs,
                                                    const unsigned short* __restrict__ wks,
                                                    const unsigned short* __restrict__ wvs,
                                                    unsigned short* __restrict__ Q2,
                                                    unsigned short* __restrict__ K2,
                                                    float* __restrict__ V) {
    const int z = blockIdx.z;
    const unsigned short* W2 = (z == 0) ? wqs : (z == 1) ? wks : wvs;
    const size_t XPL = (size_t)NPT * EMB;
    const size_t WPL = 262144;
    const size_t OPL = (size_t)NH * NPT * HD;

    const int nb = blockIdx.x * 128;
    const int ebk = blockIdx.y;
    const int tid = threadIdx.x;
    const int wv = tid >> 6, lane = tid & 63;
    const int m = lane & 15, quad = lane >> 4;
    const int n0 = nb + wv * 32;

    __shared__ __align__(16) unsigned short Ws[2][2 * 2048];   // 2 x 8 KB

    auto prefetchW = [&](int kc, int buf) {     // 8 chunks: 2 per wave
#pragma unroll
        for (int i2 = 0; i2 < 2; ++i2) {
            int c = wv + 4 * i2;
            int p = c >> 2, sub = c & 3;
            const unsigned short* src = W2 + (size_t)p * WPL
                + ((size_t)ebk * 16 + kc) * 2048 + (sub * 64 + lane) * 8;
            async_ld16(src, &Ws[buf][p * 2048 + sub * 512]);
        }
    };
    f16x8 bfA[2][2], bfB[2][2];
    auto load_bf = [&](f16x8 (&bf)[2][2], int kc) {
#pragma unroll
        for (int nt = 0; nt < 2; ++nt)
#pragma unroll
            for (int p = 0; p < 2; ++p)
                bf[nt][p] = *(const f16x8*)(xs + (size_t)p * XPL
                    + (size_t)(n0 + nt * 16 + m) * EMB + kc * 32 + quad * 8);
    };

    f32x4 acc[2][4][2];                         // [plane-sum][mt][nt]
#pragma unroll
    for (int s = 0; s < 2; ++s)
#pragma unroll
        for (int mt = 0; mt < 4; ++mt)
#pragma unroll
            for (int nt = 0; nt < 2; ++nt) acc[s][mt][nt] = (f32x4){0.f, 0.f, 0.f, 0.f};

    prefetchW(0, 0);
    load_bf(bfA, 0);

    auto iter = [&](int kc, int buf, f16x8 (&cur)[2][2], f16x8 (&nxt)[2][2]) {
        // own 2 W-chunks done; 4 bf loads for this kc stay in flight
        asm volatile("s_waitcnt vmcnt(4)\n\ts_barrier" ::: "memory");
        if (kc < 15) { prefetchW(kc + 1, buf ^ 1); load_bf(nxt, kc + 1); }
#pragma unroll
        for (int ga = 0; ga < 2; ++ga) {        // ga = W plane
            f16x8 af[4];
#pragma unroll
            for (int mt = 0; mt < 4; ++mt)
                af[mt] = *(const f16x8*)&Ws[buf][ga * 2048 + (quad * 64 + mt * 16 + m) * 8];
#pragma unroll
            for (int pb = 0; pb < 2 - ga; ++pb) // products: hh, hl, lh
#pragma unroll
                for (int mt = 0; mt < 4; ++mt)
#pragma unroll
                    for (int nt = 0; nt < 2; ++nt)
                        acc[ga + pb][mt][nt] = __builtin_amdgcn_mfma_f32_16x16x32_f16(
                            af[mt], cur[nt][pb], acc[ga + pb][mt][nt], 0, 0, 0);
        }
    };

#pragma unroll 1
    for (int kc2 = 0; kc2 < 16; kc2 += 2) {
        iter(kc2, 0, bfA, bfB);
        iter(kc2 + 1, 1, bfB, bfA);
    }

    const int h = ebk;
#pragma unroll
    for (int mt = 0; mt < 4; ++mt)
#pragma unroll
        for (int nt = 0; nt < 2; ++nt) {
            const int n = n0 + nt * 16 + m;
            const int d0 = mt * 16 + quad * 4;
            f32x4 a;
#pragma unroll
            for (int j = 0; j < 4; ++j)
                a[j] = fmaf(acc[1][mt][nt][j], LO_INV, acc[0][mt][nt][j]);
            if (z == 2) {
                *(f32x4*)(V + (size_t)n * EMB + ebk * 64 + d0) = a;
            } else {
                ushort4 ph, pl;
                split2(a[0], ph.x, pl.x);
                split2(a[1], ph.y, pl.y);
                split2(a[2], ph.z, pl.z);
                split2(a[3], ph.w, pl.w);
                unsigned short* O2 = (z == 0) ? Q2 : K2;
                size_t off = ((size_t)h * 128 + (n >> 5)) * 2048
                           + (d0 >> 3) * 256 + (n & 31) * 8 + (d0 & 7);
                *(ushort4*)(O2 + off)       = ph;
                *(ushort4*)(O2 + OPL + off) = pl;
            }
        }
}

// ---------------------------------------------------------------------------
// 3) masked argmax, BARRIER-FREE: no LDS, no syncs. Each wave loads its MFMA
//    K-fragments directly from global (granule-major layout == fragment
//    layout; 4x256B segments per wave-load, L2-resident 16 MB working set).
//    4 waves/SIMD of independent streams hide L2 latency by TLP. Branchless
//    select-based argmax epilogue (no divergent exec-mask churn).
// ---------------------------------------------------------------------------
__global__ __launch_bounds__(256, 4) void score_mfma(const unsigned short* __restrict__ Q2,
                                                     const unsigned short* __restrict__ K2,
                                                     const unsigned* __restrict__ bits_t,
                                                     float* __restrict__ pval,
                                                     int* __restrict__ pidx) {
    const int qb = blockIdx.x * 128;
    const int ks = blockIdx.y;
    const int tid = threadIdx.x;
    const int wv = tid >> 6, lane = tid & 63;
    const int m = lane & 15, quad = lane >> 4;
    const size_t PL = (size_t)NH * NPT * HD;
    const int kq = qb + wv * 32;

    f16x8 qf[2][2][2];                     // [nt][dc][plane]
    auto load_qf = [&](int hh) {
#pragma unroll
        for (int nt = 0; nt < 2; ++nt)
#pragma unroll
            for (int dc = 0; dc < 2; ++dc)
#pragma unroll
                for (int p = 0; p < 2; ++p)
                    qf[nt][dc][p] = *(const f16x8*)(Q2 + (size_t)p * PL
                        + ((size_t)hh * 128 + (kq >> 5)) * 2048
                        + (dc * 4 + quad) * 256 + (nt * 16 + m) * 8);
    };

    load_qf(0);

#pragma unroll 1
    for (int h = 0; h < NH; ++h) {
        float bestv[2]; int besti[2];
        bestv[0] = bestv[1] = -FLT_MAX;
        besti[0] = besti[1] = 0;

#pragma unroll
        for (int kst = 0; kst < 4; ++kst) {
            const int kbase = ks * 128 + kst * 32;
            const unsigned short* kb = K2 + ((size_t)h * 128 + ks * 4 + kst) * 2048;

            unsigned bw[2];                // coalesced: lanes -> consecutive q
#pragma unroll
            for (int nt = 0; nt < 2; ++nt)
                bw[nt] = bits_t[(size_t)(ks * 4 + kst) * NPT + kq + nt * 16 + m];

            f32x4 acc[2][2][2];            // [plane-sum][mt][nt]
#pragma unroll
            for (int s = 0; s < 2; ++s)
#pragma unroll
                for (int mt = 0; mt < 2; ++mt)
#pragma unroll
                    for (int nt = 0; nt < 2; ++nt) acc[s][mt][nt] = (f32x4){0.f, 0.f, 0.f, 0.f};

#pragma unroll
            for (int ga = 0; ga < 2; ++ga) {   // ga = K plane
                f16x8 kf[2][2];
#pragma unroll
                for (int mt = 0; mt < 2; ++mt)
#pragma unroll
                    for (int dc = 0; dc < 2; ++dc)
                        kf[mt][dc] = *(const f16x8*)(kb + (size_t)ga * PL
                            + (dc * 4 + quad) * 256 + (mt * 16 + m) * 8);
#pragma unroll
                for (int pb = 0; pb < 2 - ga; ++pb)   // products: hh, hl, lh
#pragma unroll
                    for (int dc = 0; dc < 2; ++dc)
#pragma unroll
                        for (int mt = 0; mt < 2; ++mt)
#pragma unroll
                            for (int nt = 0; nt < 2; ++nt)
                                acc[ga + pb][mt][nt] = __builtin_amdgcn_mfma_f32_16x16x32_f16(
                                    kf[mt][dc], qf[nt][dc][pb], acc[ga + pb][mt][nt], 0, 0, 0);
            }

            // C: col=lane&15 -> q; row=quad*4+r -> k. Branchless argmax update.
            const int idxb = kbase + quad * 4;
#pragma unroll
            for (int nt = 0; nt < 2; ++nt) {
                unsigned wq = bw[nt] >> (quad * 4);
#pragma unroll
                for (int mt = 0; mt < 2; ++mt) {
                    f32x4 a0 = acc[0][mt][nt], a1 = acc[1][mt][nt];
#pragma unroll
                    for (int r = 0; r < 4; ++r) {
                        float s = fmaf(a1[r], LO_INV, a0[r]);
                        bool ok = (wq >> (mt * 16 + r)) & 1u;
                        s = ok ? s : -FLT_MAX;
                        int idx = idxb + mt * 16 + r;
                        bool g = s > bestv[nt];
                        bestv[nt] = g ? s : bestv[nt];
                        besti[nt] = g ? idx : besti[nt];
                    }
                }
            }
        }

        if (h + 1 < NH) load_qf(h + 1);    // overlap next head's Q with reduce

        // end of head: reduce over quad groups
#pragma unroll
        for (int nt = 0; nt < 2; ++nt) {
            float v = bestv[nt]; int bi = besti[nt];
#pragma unroll
            for (int off = 16; off < 64; off <<= 1) {
                float ov = __shfl_xor(v, off);
                int   oi = __shfl_xor(bi, off);
                if (ov > v || (ov == v && oi < bi)) { v = ov; bi = oi; }
            }
            if (quad == 0) {
                size_t o = ((size_t)h * KSPLIT + ks) * NPT + kq + nt * 16 + m;
                pval[o] = v; pidx[o] = bi;
            }
        }
    }
}

// ---------------------------------------------------------------------------
// 4) reduce k-split partials (parallel 32-lane shuffle, not serial loop),
//    gather winner V row * (1/NH)
// ---------------------------------------------------------------------------
__global__ __launch_bounds__(256) void gather_out(const float* __restrict__ V,
                                                  const float* __restrict__ pval,
                                                  const int* __restrict__ pidx,
                                                  float* __restrict__ out) {
    const int q = blockIdx.x;
    const int tid = threadIdx.x;            // tid = h*32 + ks
    __shared__ int widx[NH];
    {
        const int h = tid >> 5, ksl = tid & 31;
        size_t off = ((size_t)h * KSPLIT + ksl) * NPT + q;
        float v = pval[off]; int bi = pidx[off];
#pragma unroll
        for (int o = 1; o < 32; o <<= 1) {  // stays within each 32-lane group
            float ov = __shfl_xor(v, o);
            int   oi = __shfl_xor(bi, o);
            if (ov > v || (ov == v && oi < bi)) { v = ov; bi = oi; }
        }
        if (ksl == 0) widx[h] = bi;
    }
    __syncthreads();
    if (tid < 128) {
        const int h = tid >> 4;
        const int d4 = (tid & 15) * 4;
        const int k = widx[h];
        float4 v = *(const float4*)(V + (size_t)k * EMB + h * HD + d4);
        v.x *= 0.125f; v.y *= 0.125f; v.z *= 0.125f; v.w *= 0.125f;
        *(float4*)(out + (size_t)q * EMB + h * HD + d4) = v;
    }
}

// ---------------------------------------------------------------------------
extern "C" void kernel_launch(void* const* d_in, const int* in_sizes, int n_in,
                              void* d_out, int out_size, void* d_ws, size_t ws_size,
                              hipStream_t stream) {
    const float* x   = (const float*)d_in[0];
    const int*   adj = (const int*)d_in[1];
    const float* WQ  = (const float*)d_in[2];
    const float* WK  = (const float*)d_in[3];
    const float* WV  = (const float*)d_in[4];
    // we/be are dead: energy is constant along k -> argmax unchanged.
    float* out = (float*)d_out;

    char* ws = (char*)d_ws;
    const size_t HMB = 512u * 1024;
    unsigned short* xs   = (unsigned short*)(ws);                 // 8 MB (dead after gemm)
    unsigned short* wqs  = (unsigned short*)(ws + 16 * HMB);      // 1 MB
    unsigned short* wks  = (unsigned short*)(ws + 18 * HMB);
    unsigned short* wvs  = (unsigned short*)(ws + 20 * HMB);
    unsigned short* Q2   = (unsigned short*)(ws + 22 * HMB);      // 8 MB granule-major
    unsigned short* K2   = (unsigned short*)(ws + 38 * HMB);      // 8 MB granule-major
    float*          V    = (float*)(ws + 54 * HMB);               // 8 MB
    unsigned*       bits = (unsigned*)(ws + 70 * HMB);            // 2 MB transposed
    float*          pval = (float*)(ws);                          // 4 MB, aliases dead xs
    int*            pidx = (int*)(ws + 8 * HMB);                  // 4 MB, aliases dead xs

    prep_kernel<<<dim3(2048, 5), dim3(256), 0, stream>>>(x, WQ, WK, WV, adj,
                                                         xs, wqs, wks, wvs, bits);
    gemm_mfma<<<dim3(NPT / 128, NH, 3), dim3(256), 0, stream>>>(xs, wqs, wks, wvs, Q2, K2, V);
    score_mfma<<<dim3(NPT / 128, KSPLIT), dim3(256), 0, stream>>>(Q2, K2, bits, pval, pidx);
    gather_out<<<dim3(NPT), dim3(256), 0, stream>>>(V, pval, pidx, out);
}

// Round 3
// 250.247 us; speedup vs baseline: 1.6843x; 1.6843x over previous
//
#include <hip/hip_runtime.h>
#include <hip/hip_bf16.h>
#include <float.h>
#include <stdint.h>

#define NPT    4096
#define EMB    512
#define NH     8
#define HD     64
#define KSPLIT 64     // score k-range split: KRANGE = 64 (2 tiles of 32)

typedef __attribute__((ext_vector_type(8))) _Float16 f16x8;
typedef __attribute__((ext_vector_type(4))) float f32x4;
typedef __attribute__((ext_vector_type(16))) float f32x16;
typedef uint32_t u32;

// low plane is stored scaled by 2^11 (exact) so it stays in fp16 normal range;
// recombine with s = hi_acc + lo_acc * 2^-11.
#define LO_SCALE 2048.0f
#define LO_INV   4.8828125e-4f   // 2^-11

// async global->LDS DMA, 16B/lane. LDS dest = wave-uniform base + lane*16.
__device__ __forceinline__ void async_ld16(const void* gsrc, void* ldst) {
    __builtin_amdgcn_global_load_lds(
        (const __attribute__((address_space(1))) u32*)gsrc,
        (__attribute__((address_space(3))) u32*)ldst, 16, 0, 0);
}

// fp16x2 split: a ~= h + l/2048, |err| <= 2^-22 |a|. 3-product GEMM drops
// l*l (~2^-22 per term, random sign) -> end-to-end error is fp32-accum-noise
// dominated, same regime as the fp32 reference.
__device__ __forceinline__ void split2(float a, unsigned short& h, unsigned short& l) {
    _Float16 fh = (_Float16)a;
    float r = (a - (float)fh) * LO_SCALE;
    _Float16 fl = (_Float16)r;
    h = *reinterpret_cast<unsigned short*>(&fh);
    l = *reinterpret_cast<unsigned short*>(&fl);
}

// ---------------------------------------------------------------------------
// 1) fused prep: y=0 split x; y=1..3 split W (granule-major); y=4 pack adj
//    into TRANSPOSED bitmask bits_t[kword(128)][q(4096)]
// ---------------------------------------------------------------------------
__global__ __launch_bounds__(256) void prep_kernel(const float* __restrict__ x,
                                                   const float* __restrict__ wq,
                                                   const float* __restrict__ wk,
                                                   const float* __restrict__ wv,
                                                   const int* __restrict__ adj,
                                                   unsigned short* __restrict__ xs,
                                                   unsigned short* __restrict__ wqs,
                                                   unsigned short* __restrict__ wks,
                                                   unsigned short* __restrict__ wvs,
                                                   unsigned* __restrict__ bits_t) {
    int y = blockIdx.y;
    size_t i = (size_t)blockIdx.x * 256 + threadIdx.x;
    if (y == 4) {                               // pack adj (reads coalesced)
        int q = (int)(i >> 7), w = (int)i & 127;
        const int4* p = (const int4*)(adj + (size_t)q * NPT + w * 32);
        unsigned m = 0;
#pragma unroll
        for (int j = 0; j < 8; ++j) {
            int4 v = p[j];
            m |= (v.x != 0 ? 1u : 0u) << (j * 4 + 0);
            m |= (v.y != 0 ? 1u : 0u) << (j * 4 + 1);
            m |= (v.z != 0 ? 1u : 0u) << (j * 4 + 2);
            m |= (v.w != 0 ? 1u : 0u) << (j * 4 + 3);
        }
        bits_t[(size_t)w * NPT + q] = m;        // transposed write (2 MB, cheap)
    } else if (y == 0) {
        const size_t PL = (size_t)NPT * EMB;
        float4 v = ((const float4*)x)[i];
        ushort4 h, l;
        split2(v.x, h.x, l.x);
        split2(v.y, h.y, l.y);
        split2(v.z, h.z, l.z);
        split2(v.w, h.w, l.w);
        ((ushort4*)xs)[i]        = h;
        ((ushort4*)(xs + PL))[i] = l;
    } else {
        const size_t WPL = 262144;
        if (i >= WPL / 4) return;
        const float* src = (y == 1) ? wq : (y == 2) ? wk : wv;
        unsigned short* dst = (y == 1) ? wqs : (y == 2) ? wks : wvs;
        float4 v = ((const float4*)src)[i];
        int e  = (int)(i >> 7);
        int k0 = ((int)i & 127) * 4;
        int ebk = e >> 6, el = e & 63;
        int kc = k0 >> 5, g = (k0 >> 3) & 3, dd = k0 & 7;
        size_t off = ((((size_t)ebk * 16 + kc) * 4 + g) * 64 + el) * 8 + dd;
        ushort4 h, l;
        split2(v.x, h.x, l.x);
        split2(v.y, h.y, l.y);
        split2(v.z, h.z, l.z);
        split2(v.w, h.w, l.w);
        *(ushort4*)(dst + off)       = h;
        *(ushort4*)(dst + WPL + off) = l;
    }
}

// ---------------------------------------------------------------------------
// 2) projections via fp16x2 3-product MFMA. Counted-vmcnt barrier (no drain).
//    Q2/K2 granule-major: [h][t32(128)][dg(8)][i32(32)][8shorts], 2 planes.
// ---------------------------------------------------------------------------
__global__ __launch_bounds__(256, 3) void gemm_mfma(const unsigned short* __restrict__ xs,
                                                    const unsigned short* __restrict__ wqs,
                                                    const unsigned short* __restrict__ wks,
                                                    const unsigned short* __restrict__ wvs,
                                                    unsigned short* __restrict__ Q2,
                                                    unsigned short* __restrict__ K2,
                                                    float* __restrict__ V) {
    const int z = blockIdx.z;
    const unsigned short* W2 = (z == 0) ? wqs : (z == 1) ? wks : wvs;
    const size_t XPL = (size_t)NPT * EMB;
    const size_t WPL = 262144;
    const size_t OPL = (size_t)NH * NPT * HD;

    const int nb = blockIdx.x * 128;
    const int ebk = blockIdx.y;
    const int tid = threadIdx.x;
    const int wvi = tid >> 6, lane = tid & 63;
    const int m = lane & 15, quad = lane >> 4;
    const int n0 = nb + wvi * 32;

    __shared__ __align__(16) unsigned short Ws[2][2 * 2048];   // 2 x 8 KB

    auto prefetchW = [&](int kc, int buf) {     // 8 chunks: 2 per wave
#pragma unroll
        for (int i2 = 0; i2 < 2; ++i2) {
            int c = wvi + 4 * i2;
            int p = c >> 2, sub = c & 3;
            const unsigned short* src = W2 + (size_t)p * WPL
                + ((size_t)ebk * 16 + kc) * 2048 + (sub * 64 + lane) * 8;
            async_ld16(src, &Ws[buf][p * 2048 + sub * 512]);
        }
    };
    f16x8 bfA[2][2], bfB[2][2];
    auto load_bf = [&](f16x8 (&bf)[2][2], int kc) {
#pragma unroll
        for (int nt = 0; nt < 2; ++nt)
#pragma unroll
            for (int p = 0; p < 2; ++p)
                bf[nt][p] = *(const f16x8*)(xs + (size_t)p * XPL
                    + (size_t)(n0 + nt * 16 + m) * EMB + kc * 32 + quad * 8);
    };

    f32x4 acc[2][4][2];                         // [plane-sum][mt][nt]
#pragma unroll
    for (int s = 0; s < 2; ++s)
#pragma unroll
        for (int mt = 0; mt < 4; ++mt)
#pragma unroll
            for (int nt = 0; nt < 2; ++nt) acc[s][mt][nt] = (f32x4){0.f, 0.f, 0.f, 0.f};

    prefetchW(0, 0);
    load_bf(bfA, 0);

    auto iter = [&](int kc, int buf, f16x8 (&cur)[2][2], f16x8 (&nxt)[2][2]) {
        // own 2 W-chunks done; 4 bf loads for this kc stay in flight
        asm volatile("s_waitcnt vmcnt(4)\n\ts_barrier" ::: "memory");
        if (kc < 15) { prefetchW(kc + 1, buf ^ 1); load_bf(nxt, kc + 1); }
#pragma unroll
        for (int ga = 0; ga < 2; ++ga) {        // ga = W plane
            f16x8 af[4];
#pragma unroll
            for (int mt = 0; mt < 4; ++mt)
                af[mt] = *(const f16x8*)&Ws[buf][ga * 2048 + (quad * 64 + mt * 16 + m) * 8];
#pragma unroll
            for (int pb = 0; pb < 2 - ga; ++pb) // products: hh, hl, lh
#pragma unroll
                for (int mt = 0; mt < 4; ++mt)
#pragma unroll
                    for (int nt = 0; nt < 2; ++nt)
                        acc[ga + pb][mt][nt] = __builtin_amdgcn_mfma_f32_16x16x32_f16(
                            af[mt], cur[nt][pb], acc[ga + pb][mt][nt], 0, 0, 0);
        }
    };

#pragma unroll 1
    for (int kc2 = 0; kc2 < 16; kc2 += 2) {
        iter(kc2, 0, bfA, bfB);
        iter(kc2 + 1, 1, bfB, bfA);
    }

    const int h = ebk;
#pragma unroll
    for (int mt = 0; mt < 4; ++mt)
#pragma unroll
        for (int nt = 0; nt < 2; ++nt) {
            const int n = n0 + nt * 16 + m;
            const int d0 = mt * 16 + quad * 4;
            f32x4 a;
#pragma unroll
            for (int j = 0; j < 4; ++j)
                a[j] = fmaf(acc[1][mt][nt][j], LO_INV, acc[0][mt][nt][j]);
            if (z == 2) {
                *(f32x4*)(V + (size_t)n * EMB + ebk * 64 + d0) = a;
            } else {
                ushort4 ph, pl;
                split2(a[0], ph.x, pl.x);
                split2(a[1], ph.y, pl.y);
                split2(a[2], ph.z, pl.z);
                split2(a[3], ph.w, pl.w);
                unsigned short* O2 = (z == 0) ? Q2 : K2;
                size_t off = ((size_t)h * 128 + (n >> 5)) * 2048
                           + (d0 >> 3) * 256 + (n & 31) * 8 + (d0 & 7);
                *(ushort4*)(O2 + off)       = ph;
                *(ushort4*)(O2 + OPL + off) = pl;
            }
        }
}

// ---------------------------------------------------------------------------
// 3) masked argmax via fp16x2 3-product 32x32x16 MFMA (12 MFMA/tile).
//    LDS triple-buffered K tiles (global_load_lds DMA), counted vmcnt+barrier
//    (prefetch distance 2; drains fully only on the last tile). Each lane
//    owns one q column (C: col=lane&31 -> q; row=(reg&3)+8*(reg>>2)+4*hi -> k),
//    so per-head reduce is a single lane^32 shuffle. LDS padded to 10KB/buf
//    so the LDS limit (5 blocks/CU) sets the allocator's occupancy target
//    (~102 VGPR) -- avoids the R2 spill-at-64 failure.
// ---------------------------------------------------------------------------
__global__ __launch_bounds__(256, 4) void score_mfma(const unsigned short* __restrict__ Q2,
                                                     const unsigned short* __restrict__ K2,
                                                     const unsigned* __restrict__ bits_t,
                                                     float* __restrict__ pval,
                                                     int* __restrict__ pidx) {
    const int qb = blockIdx.x * 128;
    const int ks = blockIdx.y;
    const int tid = threadIdx.x;
    const int wvi = tid >> 6, lane = tid & 63;
    const int il = lane & 31, hi = lane >> 5;
    const size_t PL = (size_t)NH * NPT * HD;
    const int q0 = qb + wvi * 32;              // wave's 32 q rows
    const int NT = NH * 2;                     // 2 k-tiles per head

    __shared__ __align__(16) unsigned short Ks[3][2 * 2048 + 1024];  // 3 x 10 KB (padded)

    auto prefetchK = [&](int t) {          // 2 DMA chunks per wave per tile
        int h = t >> 1, kt = ks * 2 + (t & 1), buf = t % 3;
#pragma unroll
        for (int i2 = 0; i2 < 2; ++i2) {
            int c = wvi + 4 * i2;
            int p = c >> 2, sub = c & 3;
            const unsigned short* src = K2 + (size_t)p * PL
                + ((size_t)h * 128 + kt) * 2048 + (sub * 64 + lane) * 8;
            async_ld16(src, &Ks[buf][p * 2048 + sub * 512]);
        }
    };

    f16x8 qf[4][2];                        // [k-chunk][plane]
    auto load_qf = [&](int hh) {
#pragma unroll
        for (int c = 0; c < 4; ++c)
#pragma unroll
            for (int p = 0; p < 2; ++p)
                qf[c][p] = *(const f16x8*)(Q2 + (size_t)p * PL
                    + ((size_t)hh * 128 + (q0 >> 5)) * 2048
                    + (c * 2 + hi) * 256 + il * 8);
    };

    load_qf(0);                            // oldest vmem (drained at t=0 wait)
    prefetchK(0);
    prefetchK(1);

    float bestv = -FLT_MAX; int besti = 0;

#pragma unroll 1
    for (int t = 0; t < NT; ++t) {
        const int h = t >> 1, kst = t & 1, buf = t % 3;
        const int kbase = ks * 64 + kst * 32;

        // own tile's 2 chunks (+older qf) done; next tile's 2 stay in flight.
        if (t + 1 < NT) asm volatile("s_waitcnt vmcnt(2)\n\ts_barrier" ::: "memory");
        else            asm volatile("s_waitcnt vmcnt(0)\n\ts_barrier" ::: "memory");

        if (kst == 0) { bestv = -FLT_MAX; besti = 0; }

        // mask word for this lane's q (lanes 0..31 / 32..63 read same 128B)
        unsigned w = bits_t[(size_t)(ks * 2 + kst) * NPT + q0 + il];

        f32x16 acc0, acc1;                 // hh | hl+lh
#pragma unroll
        for (int j = 0; j < 16; ++j) { acc0[j] = 0.f; acc1[j] = 0.f; }

        __builtin_amdgcn_s_setprio(1);
#pragma unroll
        for (int c = 0; c < 4; ++c) {      // K-dim chunks of 16
            f16x8 kfh = *(const f16x8*)&Ks[buf][(c * 2 + hi) * 256 + il * 8];
            f16x8 kfl = *(const f16x8*)&Ks[buf][2048 + (c * 2 + hi) * 256 + il * 8];
            acc0 = __builtin_amdgcn_mfma_f32_32x32x16_f16(kfh, qf[c][0], acc0, 0, 0, 0);
            acc1 = __builtin_amdgcn_mfma_f32_32x32x16_f16(kfh, qf[c][1], acc1, 0, 0, 0);
            acc1 = __builtin_amdgcn_mfma_f32_32x32x16_f16(kfl, qf[c][0], acc1, 0, 0, 0);
        }
        __builtin_amdgcn_s_setprio(0);

        if (kst == 1 && h + 1 < NH) load_qf(h + 1);  // after last use of qf
        if (t + 2 < NT) prefetchK(t + 2);            // youngest loads

        // C: col=lane&31 -> q; row=(r&3)+8*(r>>2)+4*hi -> k. Branchless argmax.
        const unsigned wsh = w >> (4 * hi);
        const int kbl = kbase + 4 * hi;
#pragma unroll
        for (int r = 0; r < 16; ++r) {
            float s = fmaf(acc1[r], LO_INV, acc0[r]);
            bool ok = (wsh >> ((r & 3) + 8 * (r >> 2))) & 1u;
            s = ok ? s : -FLT_MAX;
            int idx = kbl + (r & 3) + 8 * (r >> 2);
            bool g = s > bestv;
            bestv = g ? s : bestv;
            besti = g ? idx : besti;
        }

        if (kst == 1) {                    // end of head: reduce lane <-> lane+32
            float v = bestv; int bi = besti;
            float ov = __shfl_xor(v, 32);
            int   oi = __shfl_xor(bi, 32);
            if (ov > v || (ov == v && oi < bi)) { v = ov; bi = oi; }
            if (hi == 0) {
                size_t o = ((size_t)h * KSPLIT + ks) * NPT + q0 + il;
                pval[o] = v; pidx[o] = bi;
            }
        }
    }
}

// ---------------------------------------------------------------------------
// 4) reduce k-split partials (2/lane + 32-lane shuffle), gather winner V row
// ---------------------------------------------------------------------------
__global__ __launch_bounds__(256) void gather_out(const float* __restrict__ V,
                                                  const float* __restrict__ pval,
                                                  const int* __restrict__ pidx,
                                                  float* __restrict__ out) {
    const int q = blockIdx.x;
    const int tid = threadIdx.x;            // tid = h*32 + j
    __shared__ int widx[NH];
    {
        const int h = tid >> 5, j = tid & 31;
        size_t o1 = ((size_t)h * KSPLIT + j) * NPT + q;
        size_t o2 = ((size_t)h * KSPLIT + j + 32) * NPT + q;
        float v1 = pval[o1]; int b1 = pidx[o1];
        float v2 = pval[o2]; int b2 = pidx[o2];
        bool t2 = (v2 > v1);                 // b2 > b1 always, so tie keeps b1
        float v = t2 ? v2 : v1; int bi = t2 ? b2 : b1;
#pragma unroll
        for (int o = 1; o < 32; o <<= 1) {   // stays within each 32-lane group
            float ov = __shfl_xor(v, o);
            int   oi = __shfl_xor(bi, o);
            if (ov > v || (ov == v && oi < bi)) { v = ov; bi = oi; }
        }
        if (j == 0) widx[h] = bi;
    }
    __syncthreads();
    if (tid < 128) {
        const int h = tid >> 4;
        const int d4 = (tid & 15) * 4;
        const int k = widx[h];
        float4 v = *(const float4*)(V + (size_t)k * EMB + h * HD + d4);
        v.x *= 0.125f; v.y *= 0.125f; v.z *= 0.125f; v.w *= 0.125f;
        *(float4*)(out + (size_t)q * EMB + h * HD + d4) = v;
    }
}

// ---------------------------------------------------------------------------
extern "C" void kernel_launch(void* const* d_in, const int* in_sizes, int n_in,
                              void* d_out, int out_size, void* d_ws, size_t ws_size,
                              hipStream_t stream) {
    const float* x   = (const float*)d_in[0];
    const int*   adj = (const int*)d_in[1];
    const float* WQ  = (const float*)d_in[2];
    const float* WK  = (const float*)d_in[3];
    const float* WV  = (const float*)d_in[4];
    // we/be are dead: energy is constant along k -> argmax unchanged.
    float* out = (float*)d_out;

    char* ws = (char*)d_ws;
    const size_t HMB = 512u * 1024;
    unsigned short* xs   = (unsigned short*)(ws);                 // 8 MB (dead after gemm)
    unsigned short* wqs  = (unsigned short*)(ws + 16 * HMB);      // 1 MB (dead after gemm)
    unsigned short* wks  = (unsigned short*)(ws + 18 * HMB);
    unsigned short* wvs  = (unsigned short*)(ws + 20 * HMB);
    unsigned short* Q2   = (unsigned short*)(ws + 32 * HMB);      // 8 MB granule-major
    unsigned short* K2   = (unsigned short*)(ws + 48 * HMB);      // 8 MB granule-major
    float*          V    = (float*)(ws + 64 * HMB);               // 8 MB
    unsigned*       bits = (unsigned*)(ws + 80 * HMB);            // 2 MB transposed
    float*          pval = (float*)(ws);                          // 8 MB, aliases dead xs
    int*            pidx = (int*)(ws + 16 * HMB);                 // 8 MB, aliases dead w*s

    prep_kernel<<<dim3(2048, 5), dim3(256), 0, stream>>>(x, WQ, WK, WV, adj,
                                                         xs, wqs, wks, wvs, bits);
    gemm_mfma<<<dim3(NPT / 128, NH, 3), dim3(256), 0, stream>>>(xs, wqs, wks, wvs, Q2, K2, V);
    score_mfma<<<dim3(NPT / 128, KSPLIT), dim3(256), 0, stream>>>(Q2, K2, bits, pval, pidx);
    gather_out<<<dim3(NPT), dim3(256), 0, stream>>>(V, pval, pidx, out);
}

// Round 4
// 244.532 us; speedup vs baseline: 1.7236x; 1.0234x over previous
//
#include <hip/hip_runtime.h>
#include <hip/hip_bf16.h>
#include <float.h>
#include <stdint.h>

#define NPT    4096
#define EMB    512
#define NH     8
#define HD     64
#define KSPLIT 64     // score k-range split: KRANGE = 64 (2 tiles of 32)

typedef __attribute__((ext_vector_type(8))) _Float16 f16x8;
typedef __attribute__((ext_vector_type(4))) float f32x4;
typedef __attribute__((ext_vector_type(16))) float f32x16;
typedef uint32_t u32;

// low plane is stored scaled by 2^11 (exact) so it stays in fp16 normal range;
// recombine with s = hi_acc + lo_acc * 2^-11.
#define LO_SCALE 2048.0f
#define LO_INV   4.8828125e-4f   // 2^-11

// async global->LDS DMA, 16B/lane. LDS dest = wave-uniform base + lane*16.
__device__ __forceinline__ void async_ld16(const void* gsrc, void* ldst) {
    __builtin_amdgcn_global_load_lds(
        (const __attribute__((address_space(1))) u32*)gsrc,
        (__attribute__((address_space(3))) u32*)ldst, 16, 0, 0);
}

// fp16x2 split: a ~= h + l/2048, |err| <= 2^-22 |a|. 3-product GEMM drops
// l*l (~2^-22 per term, random sign) -> end-to-end error is fp32-accum-noise
// dominated, same regime as the fp32 reference.
__device__ __forceinline__ void split2(float a, unsigned short& h, unsigned short& l) {
    _Float16 fh = (_Float16)a;
    float r = (a - (float)fh) * LO_SCALE;
    _Float16 fl = (_Float16)r;
    h = *reinterpret_cast<unsigned short*>(&fh);
    l = *reinterpret_cast<unsigned short*>(&fl);
}

// ---------------------------------------------------------------------------
// 1) fused prep: y=0 split x; y=1..3 split W (granule-major); y=4 pack adj
//    into TRANSPOSED bitmask bits_t[kword(128)][q(4096)]
// ---------------------------------------------------------------------------
__global__ __launch_bounds__(256) void prep_kernel(const float* __restrict__ x,
                                                   const float* __restrict__ wq,
                                                   const float* __restrict__ wk,
                                                   const float* __restrict__ wv,
                                                   const int* __restrict__ adj,
                                                   unsigned short* __restrict__ xs,
                                                   unsigned short* __restrict__ wqs,
                                                   unsigned short* __restrict__ wks,
                                                   unsigned short* __restrict__ wvs,
                                                   unsigned* __restrict__ bits_t) {
    int y = blockIdx.y;
    size_t i = (size_t)blockIdx.x * 256 + threadIdx.x;
    if (y == 4) {                               // pack adj (reads coalesced)
        int q = (int)(i >> 7), w = (int)i & 127;
        const int4* p = (const int4*)(adj + (size_t)q * NPT + w * 32);
        unsigned m = 0;
#pragma unroll
        for (int j = 0; j < 8; ++j) {
            int4 v = p[j];
            m |= (v.x != 0 ? 1u : 0u) << (j * 4 + 0);
            m |= (v.y != 0 ? 1u : 0u) << (j * 4 + 1);
            m |= (v.z != 0 ? 1u : 0u) << (j * 4 + 2);
            m |= (v.w != 0 ? 1u : 0u) << (j * 4 + 3);
        }
        bits_t[(size_t)w * NPT + q] = m;        // transposed write (2 MB, cheap)
    } else if (y == 0) {
        const size_t PL = (size_t)NPT * EMB;
        float4 v = ((const float4*)x)[i];
        ushort4 h, l;
        split2(v.x, h.x, l.x);
        split2(v.y, h.y, l.y);
        split2(v.z, h.z, l.z);
        split2(v.w, h.w, l.w);
        ((ushort4*)xs)[i]        = h;
        ((ushort4*)(xs + PL))[i] = l;
    } else {
        const size_t WPL = 262144;
        if (i >= WPL / 4) return;
        const float* src = (y == 1) ? wq : (y == 2) ? wk : wv;
        unsigned short* dst = (y == 1) ? wqs : (y == 2) ? wks : wvs;
        float4 v = ((const float4*)src)[i];
        int e  = (int)(i >> 7);
        int k0 = ((int)i & 127) * 4;
        int ebk = e >> 6, el = e & 63;
        int kc = k0 >> 5, g = (k0 >> 3) & 3, dd = k0 & 7;
        size_t off = ((((size_t)ebk * 16 + kc) * 4 + g) * 64 + el) * 8 + dd;
        ushort4 h, l;
        split2(v.x, h.x, l.x);
        split2(v.y, h.y, l.y);
        split2(v.z, h.z, l.z);
        split2(v.w, h.w, l.w);
        *(ushort4*)(dst + off)       = h;
        *(ushort4*)(dst + WPL + off) = l;
    }
}

// ---------------------------------------------------------------------------
// 2) projections via fp16x2 3-product MFMA. Depth-2 pipeline on BOTH streams:
//    3 rotating W LDS buffers + 3 rotating bf register sets, full unroll so
//    all rotation indices are compile-time (rule: runtime-indexed ext_vector
//    arrays spill to scratch). Uniform vmcnt(6): at WAIT(kc) the loads younger
//    than {bf(kc),W(kc)} are exactly bf(kc+1)[4] + W(kc+1)[2].
// ---------------------------------------------------------------------------
__global__ __launch_bounds__(256, 3) void gemm_mfma(const unsigned short* __restrict__ xs,
                                                    const unsigned short* __restrict__ wqs,
                                                    const unsigned short* __restrict__ wks,
                                                    const unsigned short* __restrict__ wvs,
                                                    unsigned short* __restrict__ Q2,
                                                    unsigned short* __restrict__ K2,
                                                    float* __restrict__ V) {
    const int z = blockIdx.z;
    const unsigned short* W2 = (z == 0) ? wqs : (z == 1) ? wks : wvs;
    const size_t XPL = (size_t)NPT * EMB;
    const size_t WPL = 262144;
    const size_t OPL = (size_t)NH * NPT * HD;

    const int nb = blockIdx.x * 128;
    const int ebk = blockIdx.y;
    const int tid = threadIdx.x;
    const int wvi = tid >> 6, lane = tid & 63;
    const int m = lane & 15, quad = lane >> 4;
    const int n0 = nb + wvi * 32;

    __shared__ __align__(16) unsigned short Ws[3][2 * 2048];   // 3 x 8 KB

    auto prefetchW = [&](int kc, int buf) {     // 8 chunks: 2 per wave
#pragma unroll
        for (int i2 = 0; i2 < 2; ++i2) {
            int c = wvi + 4 * i2;
            int p = c >> 2, sub = c & 3;
            const unsigned short* src = W2 + (size_t)p * WPL
                + ((size_t)ebk * 16 + kc) * 2048 + (sub * 64 + lane) * 8;
            async_ld16(src, &Ws[buf][p * 2048 + sub * 512]);
        }
    };
    f16x8 bf[3][2][2];                          // rotating, statically indexed
    auto load_bf = [&](int set, int kc) {
#pragma unroll
        for (int nt = 0; nt < 2; ++nt)
#pragma unroll
            for (int p = 0; p < 2; ++p)
                bf[set][nt][p] = *(const f16x8*)(xs + (size_t)p * XPL
                    + (size_t)(n0 + nt * 16 + m) * EMB + kc * 32 + quad * 8);
    };

    f32x4 acc[2][4][2];                         // [plane-sum][mt][nt]
#pragma unroll
    for (int s = 0; s < 2; ++s)
#pragma unroll
        for (int mt = 0; mt < 4; ++mt)
#pragma unroll
            for (int nt = 0; nt < 2; ++nt) acc[s][mt][nt] = (f32x4){0.f, 0.f, 0.f, 0.f};

    // prologue: issue order matches steady state (bf before W per kc)
    load_bf(0, 0); prefetchW(0, 0);
    load_bf(1, 1); prefetchW(1, 1);

#pragma unroll
    for (int kc = 0; kc < 16; ++kc) {
        if (kc == 15) asm volatile("s_waitcnt vmcnt(0)\n\ts_barrier" ::: "memory");
        else          asm volatile("s_waitcnt vmcnt(6)\n\ts_barrier" ::: "memory");
        if (kc + 2 < 16) {                      // issue next-next early
            load_bf((kc + 2) % 3, kc + 2);
            prefetchW(kc + 2, (kc + 2) % 3);
        }
#pragma unroll
        for (int ga = 0; ga < 2; ++ga) {        // ga = W plane
            f16x8 af[4];
#pragma unroll
            for (int mt = 0; mt < 4; ++mt)
                af[mt] = *(const f16x8*)&Ws[kc % 3][ga * 2048 + (quad * 64 + mt * 16 + m) * 8];
#pragma unroll
            for (int pb = 0; pb < 2 - ga; ++pb) // products: hh, hl, lh
#pragma unroll
                for (int mt = 0; mt < 4; ++mt)
#pragma unroll
                    for (int nt = 0; nt < 2; ++nt)
                        acc[ga + pb][mt][nt] = __builtin_amdgcn_mfma_f32_16x16x32_f16(
                            af[mt], bf[kc % 3][nt][pb], acc[ga + pb][mt][nt], 0, 0, 0);
        }
    }

    const int h = ebk;
#pragma unroll
    for (int mt = 0; mt < 4; ++mt)
#pragma unroll
        for (int nt = 0; nt < 2; ++nt) {
            const int n = n0 + nt * 16 + m;
            const int d0 = mt * 16 + quad * 4;
            f32x4 a;
#pragma unroll
            for (int j = 0; j < 4; ++j)
                a[j] = fmaf(acc[1][mt][nt][j], LO_INV, acc[0][mt][nt][j]);
            if (z == 2) {
                *(f32x4*)(V + (size_t)n * EMB + ebk * 64 + d0) = a;
            } else {
                ushort4 ph, pl;
                split2(a[0], ph.x, pl.x);
                split2(a[1], ph.y, pl.y);
                split2(a[2], ph.z, pl.z);
                split2(a[3], ph.w, pl.w);
                unsigned short* O2 = (z == 0) ? Q2 : K2;
                size_t off = ((size_t)h * 128 + (n >> 5)) * 2048
                           + (d0 >> 3) * 256 + (n & 31) * 8 + (d0 & 7);
                *(ushort4*)(O2 + off)       = ph;
                *(ushort4*)(O2 + OPL + off) = pl;
            }
        }
}

// ---------------------------------------------------------------------------
// 3) masked argmax via fp16x2 3-product 32x32x16 MFMA, LDS triple-buffered K
//    (distance-2 counted vmcnt). NEW: XCD-aware block swizzle -- all 32 blocks
//    sharing one ks-slice land on the SAME XCD, making each XCD's K working
//    set a contiguous ~1 MB (L2-resident) so the per-tile DMA wait is an
//    L2 hit instead of an L3/HBM miss. Argmax tracks a 5-bit local code
//    (inline-const cndmask), decoded once per head.
// ---------------------------------------------------------------------------
__global__ __launch_bounds__(256, 4) void score_mfma(const unsigned short* __restrict__ Q2,
                                                     const unsigned short* __restrict__ K2,
                                                     const unsigned* __restrict__ bits_t,
                                                     float* __restrict__ pval,
                                                     int* __restrict__ pidx) {
    // XCD swizzle: dispatch order = bid, XCD = bid & 7 (8 XCDs, round-robin).
    // Map so each XCD owns ks in [xcd*8, xcd*8+8) -> 1 MB of K2, L2-resident.
    const int bid = blockIdx.x + 32 * blockIdx.y;     // grid = (32, 64)
    const int xcd = bid & 7, j = bid >> 3;            // j in [0,256)
    const int ks  = xcd * 8 + (j >> 5);
    const int qb  = (j & 31) * 128;

    const int tid = threadIdx.x;
    const int wvi = tid >> 6, lane = tid & 63;
    const int il = lane & 31, hi = lane >> 5;
    const size_t PL = (size_t)NH * NPT * HD;
    const int q0 = qb + wvi * 32;              // wave's 32 q rows
    const int NT = NH * 2;                     // 2 k-tiles per head

    __shared__ __align__(16) unsigned short Ks[3][2 * 2048 + 1024];  // 3 x 10 KB (padded)

    auto prefetchK = [&](int t) {          // 2 DMA chunks per wave per tile
        int h = t >> 1, kt = ks * 2 + (t & 1), buf = t % 3;
#pragma unroll
        for (int i2 = 0; i2 < 2; ++i2) {
            int c = wvi + 4 * i2;
            int p = c >> 2, sub = c & 3;
            const unsigned short* src = K2 + (size_t)p * PL
                + ((size_t)h * 128 + kt) * 2048 + (sub * 64 + lane) * 8;
            async_ld16(src, &Ks[buf][p * 2048 + sub * 512]);
        }
    };

    f16x8 qf[4][2];                        // [k-chunk][plane]
    auto load_qf = [&](int hh) {
#pragma unroll
        for (int c = 0; c < 4; ++c)
#pragma unroll
            for (int p = 0; p < 2; ++p)
                qf[c][p] = *(const f16x8*)(Q2 + (size_t)p * PL
                    + ((size_t)hh * 128 + (q0 >> 5)) * 2048
                    + (c * 2 + hi) * 256 + il * 8);
    };

    load_qf(0);                            // oldest vmem (drained at t=0 wait)
    prefetchK(0);
    prefetchK(1);

    float bestv = -FLT_MAX; int besti = 0;

#pragma unroll 1
    for (int t = 0; t < NT; ++t) {
        const int h = t >> 1, kst = t & 1, buf = t % 3;

        // own tile's 2 chunks (+older qf) done; next tile's 2 stay in flight.
        if (t + 1 < NT) asm volatile("s_waitcnt vmcnt(2)\n\ts_barrier" ::: "memory");
        else            asm volatile("s_waitcnt vmcnt(0)\n\ts_barrier" ::: "memory");

        if (kst == 0) { bestv = -FLT_MAX; besti = 0; }

        // mask word for this lane's q (lanes 0..31 / 32..63 read same 128B)
        unsigned w = bits_t[(size_t)(ks * 2 + kst) * NPT + q0 + il];

        f32x16 acc0, acc1;                 // hh | hl+lh
#pragma unroll
        for (int j2 = 0; j2 < 16; ++j2) { acc0[j2] = 0.f; acc1[j2] = 0.f; }

        __builtin_amdgcn_s_setprio(1);
#pragma unroll
        for (int c = 0; c < 4; ++c) {      // K-dim chunks of 16
            f16x8 kfh = *(const f16x8*)&Ks[buf][(c * 2 + hi) * 256 + il * 8];
            f16x8 kfl = *(const f16x8*)&Ks[buf][2048 + (c * 2 + hi) * 256 + il * 8];
            acc0 = __builtin_amdgcn_mfma_f32_32x32x16_f16(kfh, qf[c][0], acc0, 0, 0, 0);
            acc1 = __builtin_amdgcn_mfma_f32_32x32x16_f16(kfh, qf[c][1], acc1, 0, 0, 0);
            acc1 = __builtin_amdgcn_mfma_f32_32x32x16_f16(kfl, qf[c][0], acc1, 0, 0, 0);
        }
        __builtin_amdgcn_s_setprio(0);

        if (kst == 1 && h + 1 < NH) load_qf(h + 1);  // after last use of qf
        if (t + 2 < NT) prefetchK(t + 2);            // youngest loads

        // C: col=lane&31 -> q; row=(r&3)+8*(r>>2)+4*hi -> k.
        // Track 5-bit local code (kst<<4 | r); mask folded into compare.
        const unsigned wsh = w >> (4 * hi);
#pragma unroll
        for (int r = 0; r < 16; ++r) {
            float s = fmaf(acc1[r], LO_INV, acc0[r]);
            bool ok = (wsh >> ((r & 3) + 8 * (r >> 2))) & 1u;
            bool g = ok && (s > bestv);
            bestv = g ? s : bestv;
            besti = g ? (kst * 16 + r) : besti;
        }

        if (kst == 1) {                    // end of head: decode + reduce lane^32
            int code = besti;
            int bi = ks * 64 + ((code >> 4) << 5) + 4 * hi
                   + (code & 3) + ((code >> 2) & 3) * 8;
            float v = bestv;
            float ov = __shfl_xor(v, 32);
            int   oi = __shfl_xor(bi, 32);
            if (ov > v || (ov == v && oi < bi)) { v = ov; bi = oi; }
            if (hi == 0) {
                size_t o = ((size_t)h * KSPLIT + ks) * NPT + q0 + il;
                pval[o] = v; pidx[o] = bi;
            }
        }
    }
}

// ---------------------------------------------------------------------------
// 4) reduce k-split partials (2/lane + 32-lane shuffle), gather winner V row
// ---------------------------------------------------------------------------
__global__ __launch_bounds__(256) void gather_out(const float* __restrict__ V,
                                                  const float* __restrict__ pval,
                                                  const int* __restrict__ pidx,
                                                  float* __restrict__ out) {
    const int q = blockIdx.x;
    const int tid = threadIdx.x;            // tid = h*32 + j
    __shared__ int widx[NH];
    {
        const int h = tid >> 5, j = tid & 31;
        size_t o1 = ((size_t)h * KSPLIT + j) * NPT + q;
        size_t o2 = ((size_t)h * KSPLIT + j + 32) * NPT + q;
        float v1 = pval[o1]; int b1 = pidx[o1];
        float v2 = pval[o2]; int b2 = pidx[o2];
        bool t2 = (v2 > v1) || (v2 == v1 && b2 < b1);
        float v = t2 ? v2 : v1; int bi = t2 ? b2 : b1;
#pragma unroll
        for (int o = 1; o < 32; o <<= 1) {   // stays within each 32-lane group
            float ov = __shfl_xor(v, o);
            int   oi = __shfl_xor(bi, o);
            if (ov > v || (ov == v && oi < bi)) { v = ov; bi = oi; }
        }
        if (j == 0) widx[h] = bi;
    }
    __syncthreads();
    if (tid < 128) {
        const int h = tid >> 4;
        const int d4 = (tid & 15) * 4;
        const int k = widx[h];
        float4 v = *(const float4*)(V + (size_t)k * EMB + h * HD + d4);
        v.x *= 0.125f; v.y *= 0.125f; v.z *= 0.125f; v.w *= 0.125f;
        *(float4*)(out + (size_t)q * EMB + h * HD + d4) = v;
    }
}

// ---------------------------------------------------------------------------
extern "C" void kernel_launch(void* const* d_in, const int* in_sizes, int n_in,
                              void* d_out, int out_size, void* d_ws, size_t ws_size,
                              hipStream_t stream) {
    const float* x   = (const float*)d_in[0];
    const int*   adj = (const int*)d_in[1];
    const float* WQ  = (const float*)d_in[2];
    const float* WK  = (const float*)d_in[3];
    const float* WV  = (const float*)d_in[4];
    // we/be are dead: energy is constant along k -> argmax unchanged.
    float* out = (float*)d_out;

    char* ws = (char*)d_ws;
    const size_t HMB = 512u * 1024;
    unsigned short* xs   = (unsigned short*)(ws);                 // 8 MB (dead after gemm)
    unsigned short* wqs  = (unsigned short*)(ws + 16 * HMB);      // 1 MB (dead after gemm)
    unsigned short* wks  = (unsigned short*)(ws + 18 * HMB);
    unsigned short* wvs  = (unsigned short*)(ws + 20 * HMB);
    unsigned short* Q2   = (unsigned short*)(ws + 32 * HMB);      // 8 MB granule-major
    unsigned short* K2   = (unsigned short*)(ws + 48 * HMB);      // 8 MB granule-major
    float*          V    = (float*)(ws + 64 * HMB);               // 8 MB
    unsigned*       bits = (unsigned*)(ws + 80 * HMB);            // 2 MB transposed
    float*          pval = (float*)(ws);                          // 8 MB, aliases dead xs
    int*            pidx = (int*)(ws + 16 * HMB);                 // 8 MB, aliases dead w*s

    prep_kernel<<<dim3(2048, 5), dim3(256), 0, stream>>>(x, WQ, WK, WV, adj,
                                                         xs, wqs, wks, wvs, bits);
    gemm_mfma<<<dim3(NPT / 128, NH, 3), dim3(256), 0, stream>>>(xs, wqs, wks, wvs, Q2, K2, V);
    score_mfma<<<dim3(NPT / 128, KSPLIT), dim3(256), 0, stream>>>(Q2, K2, bits, pval, pidx);
    gather_out<<<dim3(NPT), dim3(256), 0, stream>>>(V, pval, pidx, out);
}

// Round 5
// 242.724 us; speedup vs baseline: 1.7365x; 1.0074x over previous
//
#include <hip/hip_runtime.h>
#include <hip/hip_bf16.h>
#include <float.h>
#include <stdint.h>

#define NPT    4096
#define EMB    512
#define NH     8
#define HD     64
#define KSPLIT 64     // score k-range split: KRANGE = 64 (one 64-k phase/head)

typedef __attribute__((ext_vector_type(8))) _Float16 f16x8;
typedef __attribute__((ext_vector_type(4))) float f32x4;
typedef __attribute__((ext_vector_type(16))) float f32x16;
typedef uint32_t u32;

// low plane is stored scaled by 2^11 (exact) so it stays in fp16 normal range;
// recombine with s = hi_acc + lo_acc * 2^-11.
#define LO_SCALE 2048.0f
#define LO_INV   4.8828125e-4f   // 2^-11

// async global->LDS DMA, 16B/lane. LDS dest = wave-uniform base + lane*16.
__device__ __forceinline__ void async_ld16(const void* gsrc, void* ldst) {
    __builtin_amdgcn_global_load_lds(
        (const __attribute__((address_space(1))) u32*)gsrc,
        (__attribute__((address_space(3))) u32*)ldst, 16, 0, 0);
}

// fp16x2 split: a ~= h + l/2048, |err| <= 2^-22 |a|. 3-product GEMM drops
// l*l (~2^-22 per term, random sign) -> end-to-end error is fp32-accum-noise
// dominated, same regime as the fp32 reference.
__device__ __forceinline__ void split2(float a, unsigned short& h, unsigned short& l) {
    _Float16 fh = (_Float16)a;
    float r = (a - (float)fh) * LO_SCALE;
    _Float16 fl = (_Float16)r;
    h = *reinterpret_cast<unsigned short*>(&fh);
    l = *reinterpret_cast<unsigned short*>(&fl);
}

// ---------------------------------------------------------------------------
// 1) fused prep: y=0 split x; y=1..3 split W (granule-major); y=4 pack adj
//    into TRANSPOSED bitmask bits_t[kword(128)][q(4096)]
// ---------------------------------------------------------------------------
__global__ __launch_bounds__(256) void prep_kernel(const float* __restrict__ x,
                                                   const float* __restrict__ wq,
                                                   const float* __restrict__ wk,
                                                   const float* __restrict__ wv,
                                                   const int* __restrict__ adj,
                                                   unsigned short* __restrict__ xs,
                                                   unsigned short* __restrict__ wqs,
                                                   unsigned short* __restrict__ wks,
                                                   unsigned short* __restrict__ wvs,
                                                   unsigned* __restrict__ bits_t) {
    int y = blockIdx.y;
    size_t i = (size_t)blockIdx.x * 256 + threadIdx.x;
    if (y == 4) {                               // pack adj (reads coalesced)
        int q = (int)(i >> 7), w = (int)i & 127;
        const int4* p = (const int4*)(adj + (size_t)q * NPT + w * 32);
        unsigned m = 0;
#pragma unroll
        for (int j = 0; j < 8; ++j) {
            int4 v = p[j];
            m |= (v.x != 0 ? 1u : 0u) << (j * 4 + 0);
            m |= (v.y != 0 ? 1u : 0u) << (j * 4 + 1);
            m |= (v.z != 0 ? 1u : 0u) << (j * 4 + 2);
            m |= (v.w != 0 ? 1u : 0u) << (j * 4 + 3);
        }
        bits_t[(size_t)w * NPT + q] = m;        // transposed write (2 MB, cheap)
    } else if (y == 0) {
        const size_t PL = (size_t)NPT * EMB;
        float4 v = ((const float4*)x)[i];
        ushort4 h, l;
        split2(v.x, h.x, l.x);
        split2(v.y, h.y, l.y);
        split2(v.z, h.z, l.z);
        split2(v.w, h.w, l.w);
        ((ushort4*)xs)[i]        = h;
        ((ushort4*)(xs + PL))[i] = l;
    } else {
        const size_t WPL = 262144;
        if (i >= WPL / 4) return;
        const float* src = (y == 1) ? wq : (y == 2) ? wk : wv;
        unsigned short* dst = (y == 1) ? wqs : (y == 2) ? wks : wvs;
        float4 v = ((const float4*)src)[i];
        int e  = (int)(i >> 7);
        int k0 = ((int)i & 127) * 4;
        int ebk = e >> 6, el = e & 63;
        int kc = k0 >> 5, g = (k0 >> 3) & 3, dd = k0 & 7;
        size_t off = ((((size_t)ebk * 16 + kc) * 4 + g) * 64 + el) * 8 + dd;
        ushort4 h, l;
        split2(v.x, h.x, l.x);
        split2(v.y, h.y, l.y);
        split2(v.z, h.z, l.z);
        split2(v.w, h.w, l.w);
        *(ushort4*)(dst + off)       = h;
        *(ushort4*)(dst + WPL + off) = l;
    }
}

// ---------------------------------------------------------------------------
// 2) projections via fp16x2 3-product MFMA. Depth-2 pipeline on BOTH streams:
//    3 rotating W LDS buffers + 3 rotating bf register sets, full unroll.
// ---------------------------------------------------------------------------
__global__ __launch_bounds__(256, 3) void gemm_mfma(const unsigned short* __restrict__ xs,
                                                    const unsigned short* __restrict__ wqs,
                                                    const unsigned short* __restrict__ wks,
                                                    const unsigned short* __restrict__ wvs,
                                                    unsigned short* __restrict__ Q2,
                                                    unsigned short* __restrict__ K2,
                                                    float* __restrict__ V) {
    const int z = blockIdx.z;
    const unsigned short* W2 = (z == 0) ? wqs : (z == 1) ? wks : wvs;
    const size_t XPL = (size_t)NPT * EMB;
    const size_t WPL = 262144;
    const size_t OPL = (size_t)NH * NPT * HD;

    const int nb = blockIdx.x * 128;
    const int ebk = blockIdx.y;
    const int tid = threadIdx.x;
    const int wvi = tid >> 6, lane = tid & 63;
    const int m = lane & 15, quad = lane >> 4;
    const int n0 = nb + wvi * 32;

    __shared__ __align__(16) unsigned short Ws[3][2 * 2048];   // 3 x 8 KB

    auto prefetchW = [&](int kc, int buf) {     // 8 chunks: 2 per wave
#pragma unroll
        for (int i2 = 0; i2 < 2; ++i2) {
            int c = wvi + 4 * i2;
            int p = c >> 2, sub = c & 3;
            const unsigned short* src = W2 + (size_t)p * WPL
                + ((size_t)ebk * 16 + kc) * 2048 + (sub * 64 + lane) * 8;
            async_ld16(src, &Ws[buf][p * 2048 + sub * 512]);
        }
    };
    f16x8 bf[3][2][2];                          // rotating, statically indexed
    auto load_bf = [&](int set, int kc) {
#pragma unroll
        for (int nt = 0; nt < 2; ++nt)
#pragma unroll
            for (int p = 0; p < 2; ++p)
                bf[set][nt][p] = *(const f16x8*)(xs + (size_t)p * XPL
                    + (size_t)(n0 + nt * 16 + m) * EMB + kc * 32 + quad * 8);
    };

    f32x4 acc[2][4][2];                         // [plane-sum][mt][nt]
#pragma unroll
    for (int s = 0; s < 2; ++s)
#pragma unroll
        for (int mt = 0; mt < 4; ++mt)
#pragma unroll
            for (int nt = 0; nt < 2; ++nt) acc[s][mt][nt] = (f32x4){0.f, 0.f, 0.f, 0.f};

    // prologue: issue order matches steady state (bf before W per kc)
    load_bf(0, 0); prefetchW(0, 0);
    load_bf(1, 1); prefetchW(1, 1);

#pragma unroll
    for (int kc = 0; kc < 16; ++kc) {
        if (kc == 15) asm volatile("s_waitcnt vmcnt(0)\n\ts_barrier" ::: "memory");
        else          asm volatile("s_waitcnt vmcnt(6)\n\ts_barrier" ::: "memory");
        if (kc + 2 < 16) {                      // issue next-next early
            load_bf((kc + 2) % 3, kc + 2);
            prefetchW(kc + 2, (kc + 2) % 3);
        }
#pragma unroll
        for (int ga = 0; ga < 2; ++ga) {        // ga = W plane
            f16x8 af[4];
#pragma unroll
            for (int mt = 0; mt < 4; ++mt)
                af[mt] = *(const f16x8*)&Ws[kc % 3][ga * 2048 + (quad * 64 + mt * 16 + m) * 8];
#pragma unroll
            for (int pb = 0; pb < 2 - ga; ++pb) // products: hh, hl, lh
#pragma unroll
                for (int mt = 0; mt < 4; ++mt)
#pragma unroll
                    for (int nt = 0; nt < 2; ++nt)
                        acc[ga + pb][mt][nt] = __builtin_amdgcn_mfma_f32_16x16x32_f16(
                            af[mt], bf[kc % 3][nt][pb], acc[ga + pb][mt][nt], 0, 0, 0);
        }
    }

    const int h = ebk;
#pragma unroll
    for (int mt = 0; mt < 4; ++mt)
#pragma unroll
        for (int nt = 0; nt < 2; ++nt) {
            const int n = n0 + nt * 16 + m;
            const int d0 = mt * 16 + quad * 4;
            f32x4 a;
#pragma unroll
            for (int j = 0; j < 4; ++j)
                a[j] = fmaf(acc[1][mt][nt][j], LO_INV, acc[0][mt][nt][j]);
            if (z == 2) {
                *(f32x4*)(V + (size_t)n * EMB + ebk * 64 + d0) = a;
            } else {
                ushort4 ph, pl;
                split2(a[0], ph.x, pl.x);
                split2(a[1], ph.y, pl.y);
                split2(a[2], ph.z, pl.z);
                split2(a[3], ph.w, pl.w);
                unsigned short* O2 = (z == 0) ? Q2 : K2;
                size_t off = ((size_t)h * 128 + (n >> 5)) * 2048
                           + (d0 >> 3) * 256 + (n & 31) * 8 + (d0 & 7);
                *(ushort4*)(O2 + off)       = ph;
                *(ushort4*)(O2 + OPL + off) = pl;
            }
        }
}

// ---------------------------------------------------------------------------
// 3) masked argmax, 8 FAT phases (one 64-k head-phase each): 24 MFMA +
//    16 KB DMA per phase. ALL per-phase loads (qf, bits, K-DMA) are issued
//    one full phase early, so each phase has exactly ONE s_waitcnt vmcnt(4)
//    at its barrier (leaves next tile's 4 chunks in flight) and NO mid-phase
//    waits -- every load gets ~a full phase (>1000 cyc) of latency cover,
//    enough for the L2-miss/L3-hit path. Natural grid mapping (32 q-tiles
//    fastest) is kept: proven L2-friendly in R3 (FETCH 39 MB); R4's swizzle
//    (147 MB, Q2 thrash) is reverted.
// ---------------------------------------------------------------------------
__global__ __launch_bounds__(256, 4) void score_mfma(const unsigned short* __restrict__ Q2,
                                                     const unsigned short* __restrict__ K2,
                                                     const unsigned* __restrict__ bits_t,
                                                     float* __restrict__ pval,
                                                     int* __restrict__ pidx) {
    const int qb = blockIdx.x * 128;
    const int ks = blockIdx.y;
    const int tid = threadIdx.x;
    const int wvi = tid >> 6, lane = tid & 63;
    const int il = lane & 31, hi = lane >> 5;
    const size_t PL = (size_t)NH * NPT * HD;
    const int q0 = qb + wvi * 32;              // wave's 32 q rows

    __shared__ __align__(16) unsigned short Ks[3][2 * 4096];   // 3 x 16 KB

    auto prefetchK = [&](int t) {          // 4 DMA chunks per wave per head-phase
        int buf = t % 3;
        const unsigned short* base = K2 + ((size_t)t * 128 + ks * 2) * 2048;
#pragma unroll
        for (int i2 = 0; i2 < 4; ++i2) {
            int c = wvi + 4 * i2;          // 16 chunks of 1 KB
            int p = c >> 3, sub = c & 7;
            async_ld16(base + (size_t)p * PL + sub * 512 + lane * 8,
                       &Ks[buf][p * 4096 + sub * 512]);
        }
    };

    f16x8 qf[4][2];                        // [16-d chunk][plane]
    auto load_qf = [&](int hh) {
#pragma unroll
        for (int c = 0; c < 4; ++c)
#pragma unroll
            for (int p = 0; p < 2; ++p)
                qf[c][p] = *(const f16x8*)(Q2 + (size_t)p * PL
                    + ((size_t)hh * 128 + (q0 >> 5)) * 2048
                    + (c * 2 + hi) * 256 + il * 8);
    };

    unsigned w0, w1;
    auto load_bits = [&](unsigned& a, unsigned& b) {
        a = bits_t[(size_t)(ks * 2 + 0) * NPT + q0 + il];
        b = bits_t[(size_t)(ks * 2 + 1) * NPT + q0 + il];
    };

    // prologue: qf(0), bits(0), K(0), K(1) -- start-wait leaves K(1) in flight
    load_qf(0);
    load_bits(w0, w1);
    prefetchK(0);
    prefetchK(1);

#pragma unroll 1
    for (int t = 0; t < NH; ++t) {
        const int buf = t % 3;

        if (t + 1 < NH) asm volatile("s_waitcnt vmcnt(4)\n\ts_barrier" ::: "memory");
        else            asm volatile("s_waitcnt vmcnt(0)\n\ts_barrier" ::: "memory");

        unsigned cw0 = w0, cw1 = w1;       // this phase's mask words (already loaded)
        float bestv = -FLT_MAX; int bestc = 0;

        // ---- k sub-tile 0 (k 0..31 of this ks range) ----
        f32x16 acc0, acc1;
#pragma unroll
        for (int j = 0; j < 16; ++j) { acc0[j] = 0.f; acc1[j] = 0.f; }
        __builtin_amdgcn_s_setprio(1);
#pragma unroll
        for (int c = 0; c < 4; ++c) {
            f16x8 kfh = *(const f16x8*)&Ks[buf][(c * 2 + hi) * 256 + il * 8];
            f16x8 kfl = *(const f16x8*)&Ks[buf][4096 + (c * 2 + hi) * 256 + il * 8];
            acc0 = __builtin_amdgcn_mfma_f32_32x32x16_f16(kfh, qf[c][0], acc0, 0, 0, 0);
            acc1 = __builtin_amdgcn_mfma_f32_32x32x16_f16(kfh, qf[c][1], acc1, 0, 0, 0);
            acc1 = __builtin_amdgcn_mfma_f32_32x32x16_f16(kfl, qf[c][0], acc1, 0, 0, 0);
        }
        __builtin_amdgcn_s_setprio(0);
        {
            const unsigned wsh = cw0 >> (4 * hi);    // w already in regs: no wait
#pragma unroll
            for (int r = 0; r < 16; ++r) {
                float s = fmaf(acc1[r], LO_INV, acc0[r]);
                bool ok = (wsh >> ((r & 3) + 8 * (r >> 2))) & 1u;
                bool g = ok && (s > bestv);
                bestv = g ? s : bestv;
                bestc = g ? r : bestc;
            }
        }

        // ---- k sub-tile 1 (k 32..63) ----
#pragma unroll
        for (int j = 0; j < 16; ++j) { acc0[j] = 0.f; acc1[j] = 0.f; }
        __builtin_amdgcn_s_setprio(1);
#pragma unroll
        for (int c = 0; c < 4; ++c) {
            f16x8 kfh = *(const f16x8*)&Ks[buf][2048 + (c * 2 + hi) * 256 + il * 8];
            f16x8 kfl = *(const f16x8*)&Ks[buf][4096 + 2048 + (c * 2 + hi) * 256 + il * 8];
            acc0 = __builtin_amdgcn_mfma_f32_32x32x16_f16(kfh, qf[c][0], acc0, 0, 0, 0);
            acc1 = __builtin_amdgcn_mfma_f32_32x32x16_f16(kfh, qf[c][1], acc1, 0, 0, 0);
            acc1 = __builtin_amdgcn_mfma_f32_32x32x16_f16(kfl, qf[c][0], acc1, 0, 0, 0);
        }
        __builtin_amdgcn_s_setprio(0);

        // issue next phase's loads NOW (one full phase of latency cover)
        if (t + 1 < NH) { load_qf(t + 1); load_bits(w0, w1); }
        if (t + 2 < NH) prefetchK(t + 2);

        {
            const unsigned wsh = cw1 >> (4 * hi);
#pragma unroll
            for (int r = 0; r < 16; ++r) {
                float s = fmaf(acc1[r], LO_INV, acc0[r]);
                bool ok = (wsh >> ((r & 3) + 8 * (r >> 2))) & 1u;
                bool g = ok && (s > bestv);
                bestv = g ? s : bestv;
                bestc = g ? (16 + r) : bestc;
            }
        }

        // decode 5-bit code -> absolute k, reduce lane^32, write partial
        {
            int bi = ks * 64 + ((bestc >> 4) << 5) + 4 * hi
                   + (bestc & 3) + ((bestc >> 2) & 3) * 8;
            float v = bestv;
            float ov = __shfl_xor(v, 32);
            int   oi = __shfl_xor(bi, 32);
            if (ov > v || (ov == v && oi < bi)) { v = ov; bi = oi; }
            if (hi == 0) {
                size_t o = ((size_t)t * KSPLIT + ks) * NPT + q0 + il;
                pval[o] = v; pidx[o] = bi;
            }
        }
    }
}

// ---------------------------------------------------------------------------
// 4) reduce k-split partials (2/lane + 32-lane shuffle), gather winner V row
// ---------------------------------------------------------------------------
__global__ __launch_bounds__(256) void gather_out(const float* __restrict__ V,
                                                  const float* __restrict__ pval,
                                                  const int* __restrict__ pidx,
                                                  float* __restrict__ out) {
    const int q = blockIdx.x;
    const int tid = threadIdx.x;            // tid = h*32 + j
    __shared__ int widx[NH];
    {
        const int h = tid >> 5, j = tid & 31;
        size_t o1 = ((size_t)h * KSPLIT + j) * NPT + q;
        size_t o2 = ((size_t)h * KSPLIT + j + 32) * NPT + q;
        float v1 = pval[o1]; int b1 = pidx[o1];
        float v2 = pval[o2]; int b2 = pidx[o2];
        bool t2 = (v2 > v1) || (v2 == v1 && b2 < b1);
        float v = t2 ? v2 : v1; int bi = t2 ? b2 : b1;
#pragma unroll
        for (int o = 1; o < 32; o <<= 1) {   // stays within each 32-lane group
            float ov = __shfl_xor(v, o);
            int   oi = __shfl_xor(bi, o);
            if (ov > v || (ov == v && oi < bi)) { v = ov; bi = oi; }
        }
        if (j == 0) widx[h] = bi;
    }
    __syncthreads();
    if (tid < 128) {
        const int h = tid >> 4;
        const int d4 = (tid & 15) * 4;
        const int k = widx[h];
        float4 v = *(const float4*)(V + (size_t)k * EMB + h * HD + d4);
        v.x *= 0.125f; v.y *= 0.125f; v.z *= 0.125f; v.w *= 0.125f;
        *(float4*)(out + (size_t)q * EMB + h * HD + d4) = v;
    }
}

// ---------------------------------------------------------------------------
extern "C" void kernel_launch(void* const* d_in, const int* in_sizes, int n_in,
                              void* d_out, int out_size, void* d_ws, size_t ws_size,
                              hipStream_t stream) {
    const float* x   = (const float*)d_in[0];
    const int*   adj = (const int*)d_in[1];
    const float* WQ  = (const float*)d_in[2];
    const float* WK  = (const float*)d_in[3];
    const float* WV  = (const float*)d_in[4];
    // we/be are dead: energy is constant along k -> argmax unchanged.
    float* out = (float*)d_out;

    char* ws = (char*)d_ws;
    const size_t HMB = 512u * 1024;
    unsigned short* xs   = (unsigned short*)(ws);                 // 8 MB (dead after gemm)
    unsigned short* wqs  = (unsigned short*)(ws + 16 * HMB);      // 1 MB (dead after gemm)
    unsigned short* wks  = (unsigned short*)(ws + 18 * HMB);
    unsigned short* wvs  = (unsigned short*)(ws + 20 * HMB);
    unsigned short* Q2   = (unsigned short*)(ws + 32 * HMB);      // 8 MB granule-major
    unsigned short* K2   = (unsigned short*)(ws + 48 * HMB);      // 8 MB granule-major
    float*          V    = (float*)(ws + 64 * HMB);               // 8 MB
    unsigned*       bits = (unsigned*)(ws + 80 * HMB);            // 2 MB transposed
    float*          pval = (float*)(ws);                          // 8 MB, aliases dead xs
    int*            pidx = (int*)(ws + 16 * HMB);                 // 8 MB, aliases dead w*s

    prep_kernel<<<dim3(2048, 5), dim3(256), 0, stream>>>(x, WQ, WK, WV, adj,
                                                         xs, wqs, wks, wvs, bits);
    gemm_mfma<<<dim3(NPT / 128, NH, 3), dim3(256), 0, stream>>>(xs, wqs, wks, wvs, Q2, K2, V);
    score_mfma<<<dim3(NPT / 128, KSPLIT), dim3(256), 0, stream>>>(Q2, K2, bits, pval, pidx);
    gather_out<<<dim3(NPT), dim3(256), 0, stream>>>(V, pval, pidx, out);
}